// Round 2
// baseline (557.022 us; speedup 1.0000x reference)
//
#include <hip/hip_runtime.h>

// PowerSpectrum: values[S,N,L,M,Q] -> out[S,N,L*Q*Q]
// out[s,n,l,q,p] = (1/sqrt(2l+1)) * sum_{m<2l+1} v[s,n,l,m,q] * v[s,n,l,m,p]
// S=4, N=2000, L=4, M=7, Q=64.
//
// v3 vs v2 (549 us, neutral vs v1): v2 proved the inner loop is NOT the
// bottleneck (LDS ~750cyc/block, VALU ~130cyc, observed ~4000cyc*CU/block).
// The gap is per-block fixed cost: 32000 tiny blocks, each {launch -> 1792B
// L3-latency load -> sync -> burst}. v3 amortizes 4x: one block per (s,n)
// (8000 blocks), stage all 4 l-tiles once (7168B, ONE sync), compute all
// four l's with compile-time l (loop fully unrolls, no switch, no runtime
// trip counts), stores spread across the block lifetime (store l=k while
// computing l=k+1).

#define PS_S 4
#define PS_N 2000
#define PS_L 4
#define PS_M 7
#define PS_Q 64

typedef float f32x4 __attribute__((ext_vector_type(4)));

__global__ __launch_bounds__(256) void PowerSpectrum_kernel(
    const float* __restrict__ values, float* __restrict__ out) {
    const int bid = blockIdx.x;              // one block per (s,n): 8000 blocks
    const float* __restrict__ vin = values + (size_t)bid * (PS_L * PS_M * PS_Q);
    float* __restrict__ o = out + (size_t)bid * (PS_L * PS_Q * PS_Q);

    __shared__ float v[PS_L * PS_M * PS_Q];  // 1792 floats = 7168 B

    const int t = threadIdx.x;
    // stage 448 float4s coalesced: round 1 all 256 threads, round 2 first 192
    {
        const f32x4* __restrict__ src = (const f32x4*)vin;
        f32x4* dst = (f32x4*)v;
        dst[t] = src[t];
        if (t < 192) dst[256 + t] = src[256 + t];
    }
    __syncthreads();                         // the ONLY sync

    const int p  = (t & 15) * 4;             // column base (float4)
    const int q0 = t >> 4;                   // row within each 16-row band

    // exact 1/sqrt(2l+1), compile-time constants (no v_rsq)
    const float cgs[PS_L] = {1.0f, 0.57735026918962576f,
                             0.44721359549995794f, 0.37796447300922722f};

    #pragma unroll
    for (int l = 0; l < PS_L; ++l) {         // compile-time l
        const int meff = 2 * l + 1;          // compile-time trip count
        const float* __restrict__ vl = &v[l * PS_M * PS_Q];
        f32x4 acc[4] = {};                   // 4 row-bands x 4 cols per thread

        #pragma unroll
        for (int m = 0; m < meff; ++m) {
            // column fragment: once per m, shared by all 4 row-bands.
            // depends only on t&15 -> 4x16-lane broadcast groups, conflict-free
            const f32x4 b = *(const f32x4*)&vl[m * PS_Q + p];
            #pragma unroll
            for (int r = 0; r < 4; ++r) {
                // 16-lane broadcast, 4 distinct consecutive banks: conflict-free
                const float a = vl[m * PS_Q + r * 16 + q0];
                acc[r] += a * b;
            }
        }

        float* __restrict__ ol = o + l * (PS_Q * PS_Q);
        const float cg = cgs[l];
        #pragma unroll
        for (int r = 0; r < 4; ++r) {
            f32x4 w = acc[r] * cg;
            // (r*16+q0)*Q + p: each wave stores 1KB contiguous; block covers
            // 16KB/l contiguous. Streaming output, zero reuse -> nontemporal.
            __builtin_nontemporal_store(w, (f32x4*)&ol[(r * 16 + q0) * PS_Q + p]);
        }
    }
}

extern "C" void kernel_launch(void* const* d_in, const int* in_sizes, int n_in,
                              void* d_out, int out_size, void* d_ws, size_t ws_size,
                              hipStream_t stream) {
    const float* values = (const float*)d_in[0];
    float* out = (float*)d_out;
    const int n_blocks = PS_S * PS_N;        // 8000 blocks, one per (s,n)
    PowerSpectrum_kernel<<<n_blocks, 256, 0, stream>>>(values, out);
}

// Round 3
// 552.501 us; speedup vs baseline: 1.0082x; 1.0082x over previous
//
#include <hip/hip_runtime.h>

// PowerSpectrum: values[S,N,L,M,Q] -> out[S,N,L*Q*Q]
// out[s,n,l,q,p] = (1/sqrt(2l+1)) * sum_{m<2l+1} v[s,n,l,m,q] * v[s,n,l,m,p]
// S=4, N=2000, L=4, M=7, Q=64.
//
// Decomposition of dur_us (R0-R2 evidence): timed graph = ws poison-fill
// (2.097 GB, ~336 us) + out poison-fill (524 MB, ~85 us) + kernel
// (~115-135 us vs 92 us write roofline). Kernel-side pipes (LDS, VALU,
// per-block overhead) are all hidden under the HBM write stream -- v2/v3's
// 2x cuts there were null.
//
// v4 = v3 structure + REGULAR stores (the single un-ablated variable):
// v1 (regular stores) = 539.9 us was best; v2/v3 (nontemporal) = 549/557.
// The 6.3 TB/s fill kernel uses regular stores (L2 write-combining); NT
// bypasses it. Clean A/B this round.

#define PS_S 4
#define PS_N 2000
#define PS_L 4
#define PS_M 7
#define PS_Q 64

typedef float f32x4 __attribute__((ext_vector_type(4)));

__global__ __launch_bounds__(256) void PowerSpectrum_kernel(
    const float* __restrict__ values, float* __restrict__ out) {
    const int bid = blockIdx.x;              // one block per (s,n): 8000 blocks
    const float* __restrict__ vin = values + (size_t)bid * (PS_L * PS_M * PS_Q);
    float* __restrict__ o = out + (size_t)bid * (PS_L * PS_Q * PS_Q);

    __shared__ float v[PS_L * PS_M * PS_Q];  // 1792 floats = 7168 B

    const int t = threadIdx.x;
    // stage 448 float4s coalesced: round 1 all 256 threads, round 2 first 192
    {
        const f32x4* __restrict__ src = (const f32x4*)vin;
        f32x4* dst = (f32x4*)v;
        dst[t] = src[t];
        if (t < 192) dst[256 + t] = src[256 + t];
    }
    __syncthreads();                         // the ONLY sync

    const int p  = (t & 15) * 4;             // column base (float4)
    const int q0 = t >> 4;                   // row within each 16-row band

    // exact 1/sqrt(2l+1), compile-time constants (no v_rsq)
    const float cgs[PS_L] = {1.0f, 0.57735026918962576f,
                             0.44721359549995794f, 0.37796447300922722f};

    #pragma unroll
    for (int l = 0; l < PS_L; ++l) {         // compile-time l
        const int meff = 2 * l + 1;          // compile-time trip count
        const float* __restrict__ vl = &v[l * PS_M * PS_Q];
        f32x4 acc[4] = {};                   // 4 row-bands x 4 cols per thread

        #pragma unroll
        for (int m = 0; m < meff; ++m) {
            // column fragment: once per m, shared by all 4 row-bands.
            // depends only on t&15 -> 16-lane broadcast groups, conflict-free
            const f32x4 b = *(const f32x4*)&vl[m * PS_Q + p];
            #pragma unroll
            for (int r = 0; r < 4; ++r) {
                // 16-lane broadcast, 4 distinct consecutive banks: conflict-free
                const float a = vl[m * PS_Q + r * 16 + q0];
                acc[r] += a * b;
            }
        }

        float* __restrict__ ol = o + l * (PS_Q * PS_Q);
        const float cg = cgs[l];
        #pragma unroll
        for (int r = 0; r < 4; ++r) {
            f32x4 w = acc[r] * cg;
            // (r*16+q0)*Q + p: one wave-store covers 1 KB contiguous (4 rows);
            // regular store -> L2 write-combining like the 6.3 TB/s fill.
            *(f32x4*)&ol[(r * 16 + q0) * PS_Q + p] = w;
        }
    }
}

extern "C" void kernel_launch(void* const* d_in, const int* in_sizes, int n_in,
                              void* d_out, int out_size, void* d_ws, size_t ws_size,
                              hipStream_t stream) {
    const float* values = (const float*)d_in[0];
    float* out = (float*)d_out;
    const int n_blocks = PS_S * PS_N;        // 8000 blocks, one per (s,n)
    PowerSpectrum_kernel<<<n_blocks, 256, 0, stream>>>(values, out);
}